// Round 3
// baseline (427.015 us; speedup 1.0000x reference)
//
#include <hip/hip_runtime.h>
#include <hip/hip_bf16.h>

// Binary BasicBlock. conv(sign,sign) via i8 MFMA (exact i32 accumulate).
// R6b (resubmit; R6 run died to infra): quarter-split fused epilogue (out1
// lives in LDS As[1], no register spill), strip-based transpose_sign
// (contiguous 896B reads), setprio around MFMA clusters. GEMM1 stays
// barrier-free with 2-deep register pipeline, B direct-from-L2 fragments.

#define CCH  256
#define PIMG 3136      // 56*56
#define MTOT 100352    // 32*3136
#define SPIX 3364      // 58*58
#define WPAD 58

typedef __attribute__((ext_vector_type(4))) int intx4;

#define GLOAD16(gp, lp) __builtin_amdgcn_global_load_lds( \
    (const __attribute__((address_space(1))) unsigned int*)(gp), \
    (__attribute__((address_space(3))) unsigned int*)(lp), 16, 0, 0)

__device__ __forceinline__ signed char sgnc(float v) {
    return (v > 0.f) ? 1 : ((v < 0.f) ? -1 : 0);
}

// ---------------- kernel 1: transpose + binarize x -> spad[cbg][n][pix][128]
// Strip blocks: 4 input rows x 128 ch each -> 896B-contiguous reads per ch.
__global__ void transpose_sign(const float* __restrict__ x,
                               const float* __restrict__ b11,
                               signed char* __restrict__ spad) {
    const int s   = blockIdx.x;         // 0..14 (14 strips + border block)
    const int cbg = blockIdx.y;         // 0..1 (128 ch each)
    const int n   = blockIdx.z;         // 0..31
    const int t   = threadIdx.x;        // 256
    __shared__ __align__(16) signed char tile[128 * 228];   // pitch 228 (odd dwords)

    const size_t obase = ((size_t)cbg * 32 + n) * SPIX;

    if (s == 14) {                      // zero border rows hp = 0, 57
        for (int it = 0; it < 15; ++it) {
            int lin = it * 256 + t;     // 2*58*32 = 3712 ints
            if (lin >= 3712) break;
            int r    = lin / 1856;
            int rest = lin - r * 1856;
            int wp   = rest >> 5;
            int c4   = (rest & 31) * 4;
            int hp   = r ? 57 : 0;
            *(int*)(spad + (obase + hp * WPAD + wp) * 128 + c4) = 0;
        }
        return;
    }

    const int h0 = s * 4;               // input rows h0..h0+3
    for (int it = 0; it < 28; ++it) {   // 128 ch * 4 r * 14 col4 = 7168
        int lin  = it * 256 + t;
        int c    = lin / 56;
        int rest = lin - c * 56;
        int r    = rest / 14;
        int col4 = rest - r * 14;
        int cg   = cbg * 128 + c;
        const float4 xv = *(const float4*)(x +
            ((size_t)(n * CCH + cg)) * PIMG + (h0 + r) * 56 + col4 * 4);
        float bb = b11[cg];
        int w = (sgnc(xv.x + bb) & 0xff)
              | ((sgnc(xv.y + bb) & 0xff) << 8)
              | ((sgnc(xv.z + bb) & 0xff) << 16)
              | ((sgnc(xv.w + bb) & 0xff) << 24);
        *(int*)(&tile[c * 228 + r * 56 + col4 * 4]) = w;
    }
    __syncthreads();
    for (int it = 0; it < 29; ++it) {   // 4 r * 58 wp * 32 c4 = 7424
        int lin  = it * 256 + t;
        if (lin >= 7424) break;
        int r    = lin / 1856;
        int rest = lin - r * 1856;
        int wp   = rest >> 5;
        int c4   = (rest & 31) * 4;
        int w    = 0;
        if (wp >= 1 && wp <= 56) {
            int px = r * 56 + (wp - 1);
            signed char s0 = tile[(c4 + 0) * 228 + px];
            signed char s1 = tile[(c4 + 1) * 228 + px];
            signed char s2 = tile[(c4 + 2) * 228 + px];
            signed char s3 = tile[(c4 + 3) * 228 + px];
            w = (s0 & 0xff) | ((s1 & 0xff) << 8) | ((s2 & 0xff) << 16) | ((s3 & 0xff) << 24);
        }
        *(int*)(spad + (obase + (h0 + 1 + r) * WPAD + wp) * 128 + c4) = w;
    }
}

// ---------------- kernel 2: weight binarize + BN fold -----------------------
// Fragment-ordered layouts:
// wq3f: f=(r9*2+cbg)*2+ks; byte = f*16384 + (o>>4)*1024 + quad*256 + (o&15)*16 + b
//       where c (within cbg 128) = (ks*4+quad)*16 + b
// wq1f: f=cbg*2+ks; same inner layout.
__global__ void prep_w(const float* __restrict__ w3, const float* __restrict__ w1,
                       const float* __restrict__ g1, const float* __restrict__ be1,
                       const float* __restrict__ m1, const float* __restrict__ v1,
                       const float* __restrict__ g2, const float* __restrict__ be2,
                       const float* __restrict__ m2, const float* __restrict__ v2,
                       signed char* __restrict__ wq3f, signed char* __restrict__ wq1f,
                       float* __restrict__ k2s, float* __restrict__ k2b,
                       float* __restrict__ k3s, float* __restrict__ k3b) {
    const int o = blockIdx.x;   // 0..511
    const int t = threadIdx.x;  // 256
    __shared__ float red[256];
    if (o < 256) {
        const float* wp = w3 + (size_t)o * 2304;
        float s = 0.f;
        for (int i = t; i < 2304; i += 256) s += fabsf(wp[i]);
        red[t] = s; __syncthreads();
        for (int k = 128; k > 0; k >>= 1) { if (t < k) red[t] += red[t + k]; __syncthreads(); }
        float scale = red[0] * (1.0f / 2304.0f);
        for (int i = t; i < 2304; i += 256) {
            int c = i / 9; int r9 = i - c * 9;
            int cbg = c >> 7, cl = c & 127;
            int ks = cl >> 6, qd = (cl >> 4) & 3, b = cl & 15;
            wq3f[(size_t)(((r9 * 2 + cbg) * 2 + ks)) * 16384 +
                 (o >> 4) * 1024 + qd * 256 + (o & 15) * 16 + b] = sgnc(wp[i]);
        }
        if (t == 0) {
            float inv = g1[o] * rsqrtf(v1[o] + 1e-5f);
            k2s[o] = scale * inv;
            k2b[o] = be1[o] - m1[o] * inv;
        }
    } else {
        const int o1 = o - 256;
        float w = w1[(size_t)o1 * 256 + t];
        red[t] = fabsf(w); __syncthreads();
        for (int k = 128; k > 0; k >>= 1) { if (t < k) red[t] += red[t + k]; __syncthreads(); }
        float scale = red[0] * (1.0f / 256.0f);
        int cbg = t >> 7, cl = t & 127;
        int ks = cl >> 6, qd = (cl >> 4) & 3, b = cl & 15;
        wq1f[(size_t)((cbg * 2 + ks)) * 16384 +
             (o1 >> 4) * 1024 + qd * 256 + (o1 & 15) * 16 + b] = sgnc(w);
        if (t == 0) {
            float inv = g2[o1] * rsqrtf(v2[o1] + 1e-5f);
            k3s[o1] = scale * inv;
            k3b[o1] = be2[o1] - m2[o1] * inv;
        }
    }
}

// ---------------- kernel 3: fused 3x3 + 1x1 binary conv ---------------------
// Block: 128 pixels x full 256 channels. Waves split 1M x 4N (64 o each).
// GEMM1: A (sign(x+b11) patch, both cbg = 64KB LDS) x wq3f frags (register,
// coalesced from L2), 36 barrier-free phases, 2-deep pipeline.
// Tail quarter-split (32 px each): epi1 -> out1 in LDS As[1] (32KB) + sgn in
// As[0]; GEMM2 (2 M-frags); epi2 reads out1 from LDS. No out1 registers.

#define LOADP(ph, af, bf) { \
    const int cbg_ = (ph) / 18, rem_ = (ph) % 18, r9_ = rem_ >> 1, ks_ = rem_ & 1; \
    const int shift_ = (r9_ / 3) * WPAD + (r9_ % 3); \
    const signed char* bp_ = wq3f + \
        (size_t)((((r9_ * 2 + cbg_) * 2 + ks_) * 16 + wid * 4) * 1024) + lane * 16; \
    _Pragma("unroll") \
    for (int j_ = 0; j_ < 4; ++j_) bf[j_] = *(const intx4*)(bp_ + j_ * 1024); \
    _Pragma("unroll") \
    for (int i_ = 0; i_ < 8; ++i_) { \
        const int r_  = prow[i_] + shift_; \
        const int gg_ = (ks_ * 4 + quad) ^ (r_ & 7); \
        af[i_] = *(const intx4*)(&As[cbg_][r_ * 128 + gg_ * 16]); \
    } }

#define MFMAP(af, bf) { \
    __builtin_amdgcn_s_setprio(1); \
    _Pragma("unroll") \
    for (int i_ = 0; i_ < 8; ++i_) \
        _Pragma("unroll") \
        for (int j_ = 0; j_ < 4; ++j_) \
            acc[i_][j_] = __builtin_amdgcn_mfma_i32_16x16x64_i8( \
                af[i_], bf[j_], acc[i_][j_], 0, 0, 0); \
    __builtin_amdgcn_s_setprio(0); }

#define LOADP2(ph, af, bf) { \
    const int cbg_ = (ph) >> 1, ks_ = (ph) & 1; \
    const signed char* bp_ = wq1f + \
        (size_t)(((cbg_ * 2 + ks_) * 16 + wid * 4) * 1024) + lane * 16; \
    _Pragma("unroll") \
    for (int j_ = 0; j_ < 4; ++j_) bf[j_] = *(const intx4*)(bp_ + j_ * 1024); \
    const int q16_ = cbg_ * 8 + ks_ * 4 + quad; \
    _Pragma("unroll") \
    for (int il_ = 0; il_ < 2; ++il_) { \
        const int m_ = (q * 2 + il_) * 16 + l16; \
        af[il_] = *(const intx4*)(&sgnL[m_ * 256 + ((q16_ ^ (m_ & 15)) << 4)]); \
    } }

#define MFMAP2(af, bf) { \
    __builtin_amdgcn_s_setprio(1); \
    _Pragma("unroll") \
    for (int il_ = 0; il_ < 2; ++il_) \
        _Pragma("unroll") \
        for (int j_ = 0; j_ < 4; ++j_) \
            acc2[il_][j_] = __builtin_amdgcn_mfma_i32_16x16x64_i8( \
                af[il_], bf[j_], acc2[il_][j_], 0, 0, 0); \
    __builtin_amdgcn_s_setprio(0); }

__global__ __launch_bounds__(256, 2) void gemm_fused(
    const signed char* __restrict__ spad, const signed char* __restrict__ wq3f,
    const signed char* __restrict__ wq1f, const float* __restrict__ x,
    const float* __restrict__ k2s, const float* __restrict__ k2b,
    const float* __restrict__ k3s, const float* __restrict__ k3b,
    const float* __restrict__ b12, const float* __restrict__ b13,
    const float* __restrict__ b21, const float* __restrict__ a1,
    const float* __restrict__ b22, const float* __restrict__ b23,
    const float* __restrict__ a2, float* __restrict__ out) {
    __shared__ __align__(16) signed char As[2][256 * 128];   // 64 KB
    const int t    = threadIdx.x;
    const int tile = blockIdx.x;    // 0..24
    const int n    = blockIdx.y;    // 0..31
    const int lane = t & 63;
    const int wid  = t >> 6;        // 0..3 = N-quadrant (64 o each)
    const int quad = lane >> 4;
    const int l16  = lane & 15;

    const int p0t    = tile * 128;
    const int h0     = p0t / 56;
    const int w0     = p0t - h0 * 56;
    const int pstart = h0 * WPAD + w0;

    int prow[8];
    #pragma unroll
    for (int i = 0; i < 8; ++i) {
        int p = p0t + i * 16 + l16;
        int h = p / 56, w = p - h * 56;
        prow[i] = h * WPAD + w - pstart;
    }

    const int rbase = wid * 8 + (lane >> 3);       // row mod 32
    const int gsw   = (lane & 7) ^ (rbase & 7);    // XOR swizzle via global addr

    // ---- stage A patch for both cbg: 2 x 256 rows x 128 B ----
    for (int cbg = 0; cbg < 2; ++cbg) {
        const size_t cbase = ((size_t)(cbg * 32 + n)) * SPIX + pstart;
        #pragma unroll
        for (int k = 0; k < 8; ++k) {
            const int row = k * 32 + rbase;
            const signed char* gp = spad + (cbase + row) * 128 + gsw * 16;
            GLOAD16(gp, &As[cbg][(k * 4 + wid) * 1024]);
        }
    }
    __syncthreads();

    // ---- GEMM1: 36 phases, barrier-free, 2-deep pipeline ----
    intx4 acc[8][4] = {};
    {
        intx4 afA[8], bfA[4], afB[8], bfB[4];
        LOADP(0, afA, bfA)
        #pragma unroll
        for (int ph = 0; ph < 36; ph += 2) {
            if (ph + 1 < 36) LOADP(ph + 1, afB, bfB)
            MFMAP(afA, bfA)
            if (ph + 2 < 36) LOADP(ph + 2, afA, bfA)
            if (ph + 1 < 36) MFMAP(afB, bfB)
        }
    }

    __syncthreads();   // all waves done reading As before tail overwrites it

    signed char* sgnL  = &As[0][0];            // [128 px][16 chunks][16 B]
    float*       out1L = (float*)&As[1][0];    // [256 o][32 plq] f32 = 32 KB

    #pragma unroll
    for (int q = 0; q < 4; ++q) {
        // ---- epi1(q): pixels q*32..q*32+31 ----
        #pragma unroll
        for (int j = 0; j < 4; ++j) {
            const int o = wid * 64 + j * 16 + l16;
            const float sc = k2s[o], bt = k2b[o];
            const float v12 = b12[o], v13 = b13[o], v21 = b21[o], va = a1[o];
            #pragma unroll
            for (int ii = 0; ii < 2; ++ii) {
                const int i  = q * 2 + ii;
                const int p0 = p0t + i * 16 + quad * 4;
                float rr[4] = {0.f, 0.f, 0.f, 0.f};
                if (p0 < PIMG) {
                    const float4 xv = *(const float4*)(x +
                        ((size_t)(n * CCH + o)) * PIMG + p0);
                    rr[0] = xv.x; rr[1] = xv.y; rr[2] = xv.z; rr[3] = xv.w;
                }
                const int plq = ii * 16 + quad * 4;
                float res[4];
                #pragma unroll
                for (int r = 0; r < 4; ++r) {
                    float v  = (float)acc[i][j][r] * sc + bt + rr[r];
                    float tt = v + v12;
                    float o1 = ((tt > 0.f) ? tt : va * tt) + v13;
                    res[r] = o1;
                    const int pl = i * 16 + quad * 4 + r;
                    sgnL[pl * 256 + (((wid * 4 + j) ^ (pl & 15)) << 4) + l16] =
                        sgnc(o1 + v21);
                }
                float4 ov; ov.x = res[0]; ov.y = res[1]; ov.z = res[2]; ov.w = res[3];
                *(float4*)(out1L + o * 32 + plq) = ov;
            }
        }
        __syncthreads();

        // ---- GEMM2(q): K=256 in 4 phases, 2-deep pipeline ----
        intx4 acc2[2][4] = {};
        {
            intx4 af2A[2], bf2A[4], af2B[2], bf2B[4];
            LOADP2(0, af2A, bf2A)
            #pragma unroll
            for (int ph = 0; ph < 4; ph += 2) {
                if (ph + 1 < 4) LOADP2(ph + 1, af2B, bf2B)
                MFMAP2(af2A, bf2A)
                if (ph + 2 < 4) LOADP2(ph + 2, af2A, bf2A)
                if (ph + 1 < 4) MFMAP2(af2B, bf2B)
            }
        }

        // ---- epi2(q): final out ----
        #pragma unroll
        for (int j = 0; j < 4; ++j) {
            const int o = wid * 64 + j * 16 + l16;
            const float sc = k3s[o], bt = k3b[o];
            const float v22 = b22[o], v23 = b23[o], va = a2[o];
            #pragma unroll
            for (int ii = 0; ii < 2; ++ii) {
                const int i  = q * 2 + ii;
                const int p0 = p0t + i * 16 + quad * 4;
                if (p0 >= PIMG) continue;          // padded-tile guard
                const int plq = ii * 16 + quad * 4;
                const float4 o1v = *(const float4*)(out1L + o * 32 + plq);
                float rr[4] = {o1v.x, o1v.y, o1v.z, o1v.w};
                float res[4];
                #pragma unroll
                for (int r = 0; r < 4; ++r) {
                    float v  = (float)acc2[ii][j][r] * sc + bt + rr[r];
                    float tt = v + v22;
                    res[r] = ((tt > 0.f) ? tt : va * tt) + v23;
                }
                float4 ov; ov.x = res[0]; ov.y = res[1]; ov.z = res[2]; ov.w = res[3];
                *(float4*)(out + ((size_t)(n * CCH + o)) * PIMG + p0) = ov;
            }
        }
        __syncthreads();   // protect As[0]/As[1] reuse by next quarter
    }
}

// ---------------- launch ---------------------------------------------------
extern "C" void kernel_launch(void* const* d_in, const int* in_sizes, int n_in,
                              void* d_out, int out_size, void* d_ws, size_t ws_size,
                              hipStream_t stream) {
    const float* x   = (const float*)d_in[0];
    const float* w3  = (const float*)d_in[1];
    const float* w1  = (const float*)d_in[2];
    const float* b11 = (const float*)d_in[3];
    const float* b12 = (const float*)d_in[4];
    const float* b13 = (const float*)d_in[5];
    const float* b21 = (const float*)d_in[6];
    const float* b22 = (const float*)d_in[7];
    const float* b23 = (const float*)d_in[8];
    const float* g1  = (const float*)d_in[9];
    const float* be1 = (const float*)d_in[10];
    const float* m1  = (const float*)d_in[11];
    const float* v1  = (const float*)d_in[12];
    const float* g2  = (const float*)d_in[13];
    const float* be2 = (const float*)d_in[14];
    const float* m2  = (const float*)d_in[15];
    const float* v2  = (const float*)d_in[16];
    const float* a1  = (const float*)d_in[17];
    const float* a2  = (const float*)d_in[18];
    float* out = (float*)d_out;

    char* ws = (char*)d_ws;
    // spad:  2*32*3364*128 i8 = 27,553,792 B (+256 KB staging-overrun slack)
    // wq3f:  36*16384 i8      =    589,824 B
    // wq1f:  4*16384 i8       =     65,536 B
    signed char* spad = (signed char*)(ws);
    signed char* wq3f = (signed char*)(ws + 27816192);
    signed char* wq1f = (signed char*)(ws + 28406016);
    float* k2s = (float*)(ws + 28471552);
    float* k2b = k2s + 256;
    float* k3s = k2s + 512;
    float* k3b = k2s + 768;

    transpose_sign<<<dim3(15, 2, 32), 256, 0, stream>>>(x, b11, spad);
    prep_w<<<512, 256, 0, stream>>>(w3, w1, g1, be1, m1, v1, g2, be2, m2, v2,
                                    wq3f, wq1f, k2s, k2b, k3s, k3b);
    gemm_fused<<<dim3(25, 32), 256, 0, stream>>>(spad, wq3f, wq1f, x,
                                                 k2s, k2b, k3s, k3b,
                                                 b12, b13, b21, a1,
                                                 b22, b23, a2, out);
}

// Round 4
// 304.797 us; speedup vs baseline: 1.4010x; 1.4010x over previous
//
#include <hip/hip_runtime.h>
#include <hip/hip_bf16.h>

// Binary BasicBlock. conv(sign,sign) via i8 MFMA (exact i32 accumulate).
// R7: M=64 tile (grid 49x32), acc[4][4]=64 regs -> no spill pressure
// (256-reg/wave budget at 2 waves/SIMD). out1 kept in 64 static VGPRs,
// out1L LDS buffer deleted (was 64-way bank conflicted). sgn via swizzled
// 16KB LDS. transpose_sign reverted to hp-per-block (higher occupancy).

#define CCH  256
#define PIMG 3136      // 56*56
#define SPIX 3364      // 58*58
#define WPAD 58

typedef __attribute__((ext_vector_type(4))) int intx4;

#define GLOAD16(gp, lp) __builtin_amdgcn_global_load_lds( \
    (const __attribute__((address_space(1))) unsigned int*)(gp), \
    (__attribute__((address_space(3))) unsigned int*)(lp), 16, 0, 0)

__device__ __forceinline__ signed char sgnc(float v) {
    return (v > 0.f) ? 1 : ((v < 0.f) ? -1 : 0);
}

// ---------------- kernel 1: transpose + binarize x -> spad[cbg][n][pix][128]
__global__ void transpose_sign(const float* __restrict__ x,
                               const float* __restrict__ b11,
                               signed char* __restrict__ spad) {
    const int hp  = blockIdx.x;         // 0..57
    const int cbg = blockIdx.y;         // 0..1 (128 ch each)
    const int n   = blockIdx.z;         // 0..31
    const int t   = threadIdx.x;        // 256
    __shared__ __align__(16) signed char tile[128 * 60];

    const bool border_h = (hp == 0) || (hp == 57);
    if (!border_h) {
        const int h = hp - 1;
        for (int it = 0; it < 7; ++it) {            // 128 ch * 14 col4
            int lin  = t + it * 256;
            int c    = lin / 14;
            int col4 = lin - c * 14;
            int cg   = cbg * 128 + c;
            const float4 xv = *(const float4*)(x +
                ((size_t)(n * CCH + cg)) * PIMG + h * 56 + col4 * 4);
            float bb = b11[cg];
            int w = (sgnc(xv.x + bb) & 0xff)
                  | ((sgnc(xv.y + bb) & 0xff) << 8)
                  | ((sgnc(xv.z + bb) & 0xff) << 16)
                  | ((sgnc(xv.w + bb) & 0xff) << 24);
            *(int*)(&tile[c * 60 + col4 * 4]) = w;
        }
    }
    __syncthreads();
    for (int it = 0; it < 8; ++it) {                // 58 wp * 32 c4
        int lin = t + it * 256;
        if (lin >= 58 * 32) break;
        int wp = lin >> 5;
        int c  = (lin & 31) * 4;
        int w  = 0;
        if (!border_h && wp >= 1 && wp <= 56) {
            signed char s0 = tile[(c + 0) * 60 + (wp - 1)];
            signed char s1 = tile[(c + 1) * 60 + (wp - 1)];
            signed char s2 = tile[(c + 2) * 60 + (wp - 1)];
            signed char s3 = tile[(c + 3) * 60 + (wp - 1)];
            w = (s0 & 0xff) | ((s1 & 0xff) << 8) | ((s2 & 0xff) << 16) | ((s3 & 0xff) << 24);
        }
        *(int*)(spad + (((size_t)cbg * 32 + n) * SPIX + hp * WPAD + wp) * 128 + c) = w;
    }
}

// ---------------- kernel 2: weight binarize + BN fold -----------------------
// Fragment-ordered layouts:
// wq3f: f=(r9*2+cbg)*2+ks; byte = f*16384 + (o>>4)*1024 + quad*256 + (o&15)*16 + b
//       where c (within cbg 128) = (ks*4+quad)*16 + b
// wq1f: f=cbg*2+ks; same inner layout.
__global__ void prep_w(const float* __restrict__ w3, const float* __restrict__ w1,
                       const float* __restrict__ g1, const float* __restrict__ be1,
                       const float* __restrict__ m1, const float* __restrict__ v1,
                       const float* __restrict__ g2, const float* __restrict__ be2,
                       const float* __restrict__ m2, const float* __restrict__ v2,
                       signed char* __restrict__ wq3f, signed char* __restrict__ wq1f,
                       float* __restrict__ k2s, float* __restrict__ k2b,
                       float* __restrict__ k3s, float* __restrict__ k3b) {
    const int o = blockIdx.x;   // 0..511
    const int t = threadIdx.x;  // 256
    __shared__ float red[256];
    if (o < 256) {
        const float* wp = w3 + (size_t)o * 2304;
        float s = 0.f;
        for (int i = t; i < 2304; i += 256) s += fabsf(wp[i]);
        red[t] = s; __syncthreads();
        for (int k = 128; k > 0; k >>= 1) { if (t < k) red[t] += red[t + k]; __syncthreads(); }
        float scale = red[0] * (1.0f / 2304.0f);
        for (int i = t; i < 2304; i += 256) {
            int c = i / 9; int r9 = i - c * 9;
            int cbg = c >> 7, cl = c & 127;
            int ks = cl >> 6, qd = (cl >> 4) & 3, b = cl & 15;
            wq3f[(size_t)(((r9 * 2 + cbg) * 2 + ks)) * 16384 +
                 (o >> 4) * 1024 + qd * 256 + (o & 15) * 16 + b] = sgnc(wp[i]);
        }
        if (t == 0) {
            float inv = g1[o] * rsqrtf(v1[o] + 1e-5f);
            k2s[o] = scale * inv;
            k2b[o] = be1[o] - m1[o] * inv;
        }
    } else {
        const int o1 = o - 256;
        float w = w1[(size_t)o1 * 256 + t];
        red[t] = fabsf(w); __syncthreads();
        for (int k = 128; k > 0; k >>= 1) { if (t < k) red[t] += red[t + k]; __syncthreads(); }
        float scale = red[0] * (1.0f / 256.0f);
        int cbg = t >> 7, cl = t & 127;
        int ks = cl >> 6, qd = (cl >> 4) & 3, b = cl & 15;
        wq1f[(size_t)((cbg * 2 + ks)) * 16384 +
             (o1 >> 4) * 1024 + qd * 256 + (o1 & 15) * 16 + b] = sgnc(w);
        if (t == 0) {
            float inv = g2[o1] * rsqrtf(v2[o1] + 1e-5f);
            k3s[o1] = scale * inv;
            k3b[o1] = be2[o1] - m2[o1] * inv;
        }
    }
}

// ---------------- kernel 3: fused 3x3 + 1x1 binary conv ---------------------
// Block: 64 pixels x full 256 channels. Waves split 1M x 4N (64 o each).
// GEMM1: A patch (192 rows x 128B x 2 cbg = 48KB LDS) x wq3f register frags
// (coalesced 1KB/wave from L2), 36 barrier-free phases, 2-deep pipeline,
// acc[4][4]=64 regs. Tail: epi1 -> out1 in 64 static VGPRs + sgn -> 16KB
// swizzled LDS (overlays As[0]); GEMM2 K=256 straight-line (acc2 64 regs);
// epi2 from out1 regs. Peak live ~220 < 256-reg/wave budget: no spill.

#define LOADP(ph, af, bf) { \
    const int cbg_ = (ph) / 18, rem_ = (ph) % 18, r9_ = rem_ >> 1, ks_ = rem_ & 1; \
    const int shift_ = (r9_ / 3) * WPAD + (r9_ % 3); \
    const signed char* bp_ = wq3f + \
        (size_t)((((r9_ * 2 + cbg_) * 2 + ks_) * 16 + wid * 4) * 1024) + lane * 16; \
    _Pragma("unroll") \
    for (int j_ = 0; j_ < 4; ++j_) bf[j_] = *(const intx4*)(bp_ + j_ * 1024); \
    _Pragma("unroll") \
    for (int i_ = 0; i_ < 4; ++i_) { \
        const int r_  = prow[i_] + shift_; \
        const int gg_ = (ks_ * 4 + quad) ^ (r_ & 7); \
        af[i_] = *(const intx4*)(&As[cbg_][r_ * 128 + gg_ * 16]); \
    } }

#define MFMAP(af, bf) { \
    __builtin_amdgcn_s_setprio(1); \
    _Pragma("unroll") \
    for (int i_ = 0; i_ < 4; ++i_) \
        _Pragma("unroll") \
        for (int j_ = 0; j_ < 4; ++j_) \
            acc[i_][j_] = __builtin_amdgcn_mfma_i32_16x16x64_i8( \
                af[i_], bf[j_], acc[i_][j_], 0, 0, 0); \
    __builtin_amdgcn_s_setprio(0); }

__global__ __launch_bounds__(256, 2) void gemm_fused(
    const signed char* __restrict__ spad, const signed char* __restrict__ wq3f,
    const signed char* __restrict__ wq1f, const float* __restrict__ x,
    const float* __restrict__ k2s, const float* __restrict__ k2b,
    const float* __restrict__ k3s, const float* __restrict__ k3b,
    const float* __restrict__ b12, const float* __restrict__ b13,
    const float* __restrict__ b21, const float* __restrict__ a1,
    const float* __restrict__ b22, const float* __restrict__ b23,
    const float* __restrict__ a2, float* __restrict__ out) {
    __shared__ __align__(16) signed char As[2][192 * 128];   // 48 KB
    const int t    = threadIdx.x;
    const int tile = blockIdx.x;    // 0..48 (49*64 = 3136 exact)
    const int n    = blockIdx.y;    // 0..31
    const int lane = t & 63;
    const int wid  = t >> 6;        // 0..3 = N-quadrant (64 o each)
    const int quad = lane >> 4;
    const int l16  = lane & 15;

    const int p0t    = tile * 64;
    const int h0     = p0t / 56;
    const int w0     = p0t - h0 * 56;
    const int pstart = h0 * WPAD + w0;

    int prow[4];
    #pragma unroll
    for (int i = 0; i < 4; ++i) {
        int p = p0t + i * 16 + l16;
        int h = p / 56, w = p - h * 56;
        prow[i] = h * WPAD + w - pstart;       // max 65 (+ shift 118 = 183 < 192)
    }

    const int rbase = wid * 8 + (lane >> 3);   // row mod 32
    const int gsw   = (lane & 7) ^ (rbase & 7);// XOR swizzle via global addr

    // ---- stage A patch for both cbg: 2 x 192 rows x 128 B ----
    for (int cbg = 0; cbg < 2; ++cbg) {
        const size_t cbase = ((size_t)(cbg * 32 + n)) * SPIX + pstart;
        #pragma unroll
        for (int k = 0; k < 6; ++k) {
            const int row = k * 32 + rbase;
            const signed char* gp = spad + (cbase + row) * 128 + gsw * 16;
            GLOAD16(gp, &As[cbg][(k * 4 + wid) * 1024]);
        }
    }
    __syncthreads();

    // ---- GEMM1: 36 phases, barrier-free, 2-deep pipeline ----
    intx4 acc[4][4] = {};
    {
        intx4 afA[4], bfA[4], afB[4], bfB[4];
        LOADP(0, afA, bfA)
        #pragma unroll
        for (int ph = 0; ph < 36; ph += 2) {
            if (ph + 1 < 36) LOADP(ph + 1, afB, bfB)
            MFMAP(afA, bfA)
            if (ph + 2 < 36) LOADP(ph + 2, afA, bfA)
            if (ph + 1 < 36) MFMAP(afB, bfB)
        }
    }

    __syncthreads();   // all waves done reading As before sgnL overwrites As[0]

    signed char* sgnL = &As[0][0];     // [64 px][16 chunks][16 B] = 16 KB

    // ---- epi1: out1 -> 64 static VGPRs; sign(out1+b21) -> swizzled LDS ----
    float out1r[4][4][4];
    #pragma unroll
    for (int j = 0; j < 4; ++j) {
        const int o = wid * 64 + j * 16 + l16;
        const float sc = k2s[o], bt = k2b[o];
        const float v12 = b12[o], v13 = b13[o], v21 = b21[o], va = a1[o];
        #pragma unroll
        for (int i = 0; i < 4; ++i) {
            const int p0 = p0t + i * 16 + quad * 4;
            const float4 xv = *(const float4*)(x + ((size_t)(n * CCH + o)) * PIMG + p0);
            float rr[4] = {xv.x, xv.y, xv.z, xv.w};
            #pragma unroll
            for (int r = 0; r < 4; ++r) {
                float v  = (float)acc[i][j][r] * sc + bt + rr[r];
                float tt = v + v12;
                float o1 = ((tt > 0.f) ? tt : va * tt) + v13;
                out1r[i][j][r] = o1;
                const int pl = i * 16 + quad * 4 + r;      // local pixel 0..63
                sgnL[pl * 256 + (((wid * 4 + j) ^ (pl & 15)) << 4) + l16] =
                    sgnc(o1 + v21);
            }
        }
    }
    __syncthreads();

    // ---- GEMM2: 1x1 conv, K=256 in 4 straight-line phases ----
    intx4 acc2[4][4] = {};
    #pragma unroll
    for (int ph = 0; ph < 4; ++ph) {
        const int cbg2 = ph >> 1, ks2 = ph & 1;
        intx4 af2[4], bf2[4];
        const signed char* bp = wq1f +
            (size_t)(((cbg2 * 2 + ks2) * 16 + wid * 4) * 1024) + lane * 16;
        #pragma unroll
        for (int j = 0; j < 4; ++j) bf2[j] = *(const intx4*)(bp + j * 1024);
        const int q16 = cbg2 * 8 + ks2 * 4 + quad;
        #pragma unroll
        for (int i = 0; i < 4; ++i) {
            const int m = i * 16 + l16;
            af2[i] = *(const intx4*)(&sgnL[m * 256 + ((q16 ^ (m & 15)) << 4)]);
        }
        #pragma unroll
        for (int i = 0; i < 4; ++i)
            #pragma unroll
            for (int j = 0; j < 4; ++j)
                acc2[i][j] = __builtin_amdgcn_mfma_i32_16x16x64_i8(
                    af2[i], bf2[j], acc2[i][j], 0, 0, 0);
    }

    // ---- epi2: final out from out1 regs ----
    #pragma unroll
    for (int j = 0; j < 4; ++j) {
        const int o = wid * 64 + j * 16 + l16;
        const float sc = k3s[o], bt = k3b[o];
        const float v22 = b22[o], v23 = b23[o], va = a2[o];
        #pragma unroll
        for (int i = 0; i < 4; ++i) {
            const int p0 = p0t + i * 16 + quad * 4;
            float res[4];
            #pragma unroll
            for (int r = 0; r < 4; ++r) {
                float v  = (float)acc2[i][j][r] * sc + bt + out1r[i][j][r];
                float tt = v + v22;
                res[r] = ((tt > 0.f) ? tt : va * tt) + v23;
            }
            float4 ov; ov.x = res[0]; ov.y = res[1]; ov.z = res[2]; ov.w = res[3];
            *(float4*)(out + ((size_t)(n * CCH + o)) * PIMG + p0) = ov;
        }
    }
}

// ---------------- launch ---------------------------------------------------
extern "C" void kernel_launch(void* const* d_in, const int* in_sizes, int n_in,
                              void* d_out, int out_size, void* d_ws, size_t ws_size,
                              hipStream_t stream) {
    const float* x   = (const float*)d_in[0];
    const float* w3  = (const float*)d_in[1];
    const float* w1  = (const float*)d_in[2];
    const float* b11 = (const float*)d_in[3];
    const float* b12 = (const float*)d_in[4];
    const float* b13 = (const float*)d_in[5];
    const float* b21 = (const float*)d_in[6];
    const float* b22 = (const float*)d_in[7];
    const float* b23 = (const float*)d_in[8];
    const float* g1  = (const float*)d_in[9];
    const float* be1 = (const float*)d_in[10];
    const float* m1  = (const float*)d_in[11];
    const float* v1  = (const float*)d_in[12];
    const float* g2  = (const float*)d_in[13];
    const float* be2 = (const float*)d_in[14];
    const float* m2  = (const float*)d_in[15];
    const float* v2  = (const float*)d_in[16];
    const float* a1  = (const float*)d_in[17];
    const float* a2  = (const float*)d_in[18];
    float* out = (float*)d_out;

    char* ws = (char*)d_ws;
    // spad:  2*32*3364*128 i8 = 27,553,792 B (+256 KB staging-overrun slack)
    // wq3f:  36*16384 i8      =    589,824 B
    // wq1f:  4*16384 i8       =     65,536 B
    signed char* spad = (signed char*)(ws);
    signed char* wq3f = (signed char*)(ws + 27816192);
    signed char* wq1f = (signed char*)(ws + 28406016);
    float* k2s = (float*)(ws + 28471552);
    float* k2b = k2s + 256;
    float* k3s = k2s + 512;
    float* k3b = k2s + 768;

    transpose_sign<<<dim3(58, 2, 32), 256, 0, stream>>>(x, b11, spad);
    prep_w<<<512, 256, 0, stream>>>(w3, w1, g1, be1, m1, v1, g2, be2, m2, v2,
                                    wq3f, wq1f, k2s, k2b, k3s, k3b);
    gemm_fused<<<dim3(49, 32), 256, 0, stream>>>(spad, wq3f, wq1f, x,
                                                 k2s, k2b, k3s, k3b,
                                                 b12, b13, b21, a1,
                                                 b22, b23, a2, out);
}

// Round 5
// 302.647 us; speedup vs baseline: 1.4109x; 1.0071x over previous
//
#include <hip/hip_runtime.h>
#include <hip/hip_bf16.h>

// Binary BasicBlock. conv(sign,sign) via i8 MFMA (exact i32 accumulate).
// R8: GEMM1 B-fragment ring deepened to 4 stages (prefetch dist 3 covers
// ~200cyc L2 latency); transpose_sign phase-2 rewritten with v_perm_b32
// 4x4 byte transpose (halves LDS issue count). Rest identical to R7.

#define CCH  256
#define PIMG 3136      // 56*56
#define SPIX 3364      // 58*58
#define WPAD 58

typedef __attribute__((ext_vector_type(4))) int intx4;

#define GLOAD16(gp, lp) __builtin_amdgcn_global_load_lds( \
    (const __attribute__((address_space(1))) unsigned int*)(gp), \
    (__attribute__((address_space(3))) unsigned int*)(lp), 16, 0, 0)

__device__ __forceinline__ signed char sgnc(float v) {
    return (v > 0.f) ? 1 : ((v < 0.f) ? -1 : 0);
}

// ---------------- kernel 1: transpose + binarize x -> spad[cbg][n][pix][128]
__global__ void transpose_sign(const float* __restrict__ x,
                               const float* __restrict__ b11,
                               signed char* __restrict__ spad) {
    const int hp  = blockIdx.x;         // 0..57
    const int cbg = blockIdx.y;         // 0..1 (128 ch each)
    const int n   = blockIdx.z;         // 0..31
    const int t   = threadIdx.x;        // 256
    __shared__ __align__(16) signed char tile[128 * 60];

    const size_t obase = ((size_t)cbg * 32 + n) * SPIX + (size_t)hp * WPAD;

    if (hp == 0 || hp == 57) {          // border rows: all zero
        for (int it = 0; it < 8; ++it) {
            int lin = t + it * 256;     // 58 wp * 32 c4 = 1856
            if (lin >= 1856) break;
            int wp = lin >> 5;
            int c4 = (lin & 31) * 4;
            *(int*)(spad + (obase + wp) * 128 + c4) = 0;
        }
        return;
    }

    // phase 1: read row h, sign+pack 4 px per int -> tile[c][col4]
    const int h = hp - 1;
    for (int it = 0; it < 7; ++it) {                // 128 ch * 14 col4
        int lin  = t + it * 256;
        int c    = lin / 14;
        int col4 = lin - c * 14;
        int cg   = cbg * 128 + c;
        const float4 xv = *(const float4*)(x +
            ((size_t)(n * CCH + cg)) * PIMG + h * 56 + col4 * 4);
        float bb = b11[cg];
        int w = (sgnc(xv.x + bb) & 0xff)
              | ((sgnc(xv.y + bb) & 0xff) << 8)
              | ((sgnc(xv.z + bb) & 0xff) << 16)
              | ((sgnc(xv.w + bb) & 0xff) << 24);
        *(int*)(&tile[c * 60 + col4 * 4]) = w;
    }
    __syncthreads();

    // phase 2: v_perm 4x4 byte transpose. task = (g, c4): 15*32 = 480 tasks.
    for (int it = 0; it < 2; ++it) {
        int task = t + it * 256;
        if (task >= 480) break;
        int g  = task >> 5;             // wp group: wp = 4g..4g+3, px = wp-1
        int c4 = task & 31;             // channel group c = 4*c4 .. 4*c4+3
        unsigned int w[4];
        #pragma unroll
        for (int cc = 0; cc < 4; ++cc) {
            const signed char* rowp = &tile[(c4 * 4 + cc) * 60];
            unsigned int A = (g == 0)  ? 0u : *(const unsigned int*)(rowp + (g - 1) * 4);
            unsigned int B = (g < 14)  ? *(const unsigned int*)(rowp + g * 4) : 0u;
            w[cc] = (A >> 24) | (B << 8);           // bytes: px 4g-1 .. 4g+2
        }
        unsigned int p01_0 = __builtin_amdgcn_perm(w[1], w[0], 0x05010400u);
        unsigned int p01_1 = __builtin_amdgcn_perm(w[1], w[0], 0x07030602u);
        unsigned int p23_0 = __builtin_amdgcn_perm(w[3], w[2], 0x05010400u);
        unsigned int p23_1 = __builtin_amdgcn_perm(w[3], w[2], 0x07030602u);
        unsigned int o0 = __builtin_amdgcn_perm(p23_0, p01_0, 0x05040100u);
        unsigned int o1 = __builtin_amdgcn_perm(p23_0, p01_0, 0x07060302u);
        unsigned int o2 = __builtin_amdgcn_perm(p23_1, p01_1, 0x05040100u);
        unsigned int o3 = __builtin_amdgcn_perm(p23_1, p01_1, 0x07060302u);
        unsigned int ov[4] = {o0, o1, o2, o3};
        #pragma unroll
        for (int p = 0; p < 4; ++p) {
            int wp = 4 * g + p;
            if (wp < 58)
                *(int*)(spad + (obase + wp) * 128 + c4 * 4) = (int)ov[p];
        }
    }
}

// ---------------- kernel 2: weight binarize + BN fold -----------------------
// Fragment-ordered layouts:
// wq3f: f=(r9*2+cbg)*2+ks; byte = f*16384 + (o>>4)*1024 + quad*256 + (o&15)*16 + b
//       where c (within cbg 128) = (ks*4+quad)*16 + b
// wq1f: f=cbg*2+ks; same inner layout.
__global__ void prep_w(const float* __restrict__ w3, const float* __restrict__ w1,
                       const float* __restrict__ g1, const float* __restrict__ be1,
                       const float* __restrict__ m1, const float* __restrict__ v1,
                       const float* __restrict__ g2, const float* __restrict__ be2,
                       const float* __restrict__ m2, const float* __restrict__ v2,
                       signed char* __restrict__ wq3f, signed char* __restrict__ wq1f,
                       float* __restrict__ k2s, float* __restrict__ k2b,
                       float* __restrict__ k3s, float* __restrict__ k3b) {
    const int o = blockIdx.x;   // 0..511
    const int t = threadIdx.x;  // 256
    __shared__ float red[256];
    if (o < 256) {
        const float* wp = w3 + (size_t)o * 2304;
        float s = 0.f;
        for (int i = t; i < 2304; i += 256) s += fabsf(wp[i]);
        red[t] = s; __syncthreads();
        for (int k = 128; k > 0; k >>= 1) { if (t < k) red[t] += red[t + k]; __syncthreads(); }
        float scale = red[0] * (1.0f / 2304.0f);
        for (int i = t; i < 2304; i += 256) {
            int c = i / 9; int r9 = i - c * 9;
            int cbg = c >> 7, cl = c & 127;
            int ks = cl >> 6, qd = (cl >> 4) & 3, b = cl & 15;
            wq3f[(size_t)(((r9 * 2 + cbg) * 2 + ks)) * 16384 +
                 (o >> 4) * 1024 + qd * 256 + (o & 15) * 16 + b] = sgnc(wp[i]);
        }
        if (t == 0) {
            float inv = g1[o] * rsqrtf(v1[o] + 1e-5f);
            k2s[o] = scale * inv;
            k2b[o] = be1[o] - m1[o] * inv;
        }
    } else {
        const int o1 = o - 256;
        float w = w1[(size_t)o1 * 256 + t];
        red[t] = fabsf(w); __syncthreads();
        for (int k = 128; k > 0; k >>= 1) { if (t < k) red[t] += red[t + k]; __syncthreads(); }
        float scale = red[0] * (1.0f / 256.0f);
        int cbg = t >> 7, cl = t & 127;
        int ks = cl >> 6, qd = (cl >> 4) & 3, b = cl & 15;
        wq1f[(size_t)((cbg * 2 + ks)) * 16384 +
             (o1 >> 4) * 1024 + qd * 256 + (o1 & 15) * 16 + b] = sgnc(w);
        if (t == 0) {
            float inv = g2[o1] * rsqrtf(v2[o1] + 1e-5f);
            k3s[o1] = scale * inv;
            k3b[o1] = be2[o1] - m2[o1] * inv;
        }
    }
}

// ---------------- kernel 3: fused 3x3 + 1x1 binary conv ---------------------
// Block: 64 pixels x full 256 channels. Waves split 1M x 4N (64 o each).
// GEMM1: A patch (192 rows x 128B x 2 cbg = 48KB LDS) x wq3f register frags,
// 36 barrier-free phases; B-ring 4-deep (dist 3 covers L2 latency), A 2-deep.
// acc[4][4]=64 regs. Tail: epi1 -> out1 in 64 static VGPRs + sgn -> 16KB
// swizzled LDS; GEMM2 K=256 straight-line; epi2 from out1 regs.

#define LOADB(ph, bf) { \
    const int cbg_ = (ph) / 18, rem_ = (ph) % 18, r9_ = rem_ >> 1, ks_ = rem_ & 1; \
    const signed char* bp_ = wq3f + \
        (size_t)((((r9_ * 2 + cbg_) * 2 + ks_) * 16 + wid * 4) * 1024) + lane * 16; \
    _Pragma("unroll") \
    for (int j_ = 0; j_ < 4; ++j_) bf[j_] = *(const intx4*)(bp_ + j_ * 1024); }

#define LOADA(ph, af) { \
    const int cbg_ = (ph) / 18, rem_ = (ph) % 18, r9_ = rem_ >> 1, ks_ = rem_ & 1; \
    const int shift_ = (r9_ / 3) * WPAD + (r9_ % 3); \
    _Pragma("unroll") \
    for (int i_ = 0; i_ < 4; ++i_) { \
        const int r_  = prow[i_] + shift_; \
        const int gg_ = (ks_ * 4 + quad) ^ (r_ & 7); \
        af[i_] = *(const intx4*)(&As[cbg_][r_ * 128 + gg_ * 16]); \
    } }

#define MFMAP(af, bf) { \
    __builtin_amdgcn_s_setprio(1); \
    _Pragma("unroll") \
    for (int i_ = 0; i_ < 4; ++i_) \
        _Pragma("unroll") \
        for (int j_ = 0; j_ < 4; ++j_) \
            acc[i_][j_] = __builtin_amdgcn_mfma_i32_16x16x64_i8( \
                af[i_], bf[j_], acc[i_][j_], 0, 0, 0); \
    __builtin_amdgcn_s_setprio(0); }

__global__ __launch_bounds__(256, 2) void gemm_fused(
    const signed char* __restrict__ spad, const signed char* __restrict__ wq3f,
    const signed char* __restrict__ wq1f, const float* __restrict__ x,
    const float* __restrict__ k2s, const float* __restrict__ k2b,
    const float* __restrict__ k3s, const float* __restrict__ k3b,
    const float* __restrict__ b12, const float* __restrict__ b13,
    const float* __restrict__ b21, const float* __restrict__ a1,
    const float* __restrict__ b22, const float* __restrict__ b23,
    const float* __restrict__ a2, float* __restrict__ out) {
    __shared__ __align__(16) signed char As[2][192 * 128];   // 48 KB
    const int t    = threadIdx.x;
    const int tile = blockIdx.x;    // 0..48 (49*64 = 3136 exact)
    const int n    = blockIdx.y;    // 0..31
    const int lane = t & 63;
    const int wid  = t >> 6;        // 0..3 = N-quadrant (64 o each)
    const int quad = lane >> 4;
    const int l16  = lane & 15;

    const int p0t    = tile * 64;
    const int h0     = p0t / 56;
    const int w0     = p0t - h0 * 56;
    const int pstart = h0 * WPAD + w0;

    int prow[4];
    #pragma unroll
    for (int i = 0; i < 4; ++i) {
        int p = p0t + i * 16 + l16;
        int h = p / 56, w = p - h * 56;
        prow[i] = h * WPAD + w - pstart;       // max 65 (+ shift 118 = 183 < 192)
    }

    const int rbase = wid * 8 + (lane >> 3);   // row mod 32
    const int gsw   = (lane & 7) ^ (rbase & 7);// XOR swizzle via global addr

    // ---- stage A patch for both cbg: 2 x 192 rows x 128 B ----
    for (int cbg = 0; cbg < 2; ++cbg) {
        const size_t cbase = ((size_t)(cbg * 32 + n)) * SPIX + pstart;
        #pragma unroll
        for (int k = 0; k < 6; ++k) {
            const int row = k * 32 + rbase;
            const signed char* gp = spad + (cbase + row) * 128 + gsw * 16;
            GLOAD16(gp, &As[cbg][(k * 4 + wid) * 1024]);
        }
    }
    __syncthreads();

    // ---- GEMM1: 36 phases, barrier-free; B 4-deep ring, A 2-deep ----
    intx4 acc[4][4] = {};
    {
        intx4 bfS[4][4], afS[2][4];
        LOADB(0, bfS[0])
        LOADB(1, bfS[1])
        LOADB(2, bfS[2])
        LOADA(0, afS[0])
        #pragma unroll
        for (int ph = 0; ph < 36; ++ph) {
            if (ph + 1 < 36) LOADA(ph + 1, afS[(ph + 1) & 1])
            if (ph + 3 < 36) LOADB(ph + 3, bfS[(ph + 3) & 3])
            MFMAP(afS[ph & 1], bfS[ph & 3])
        }
    }

    __syncthreads();   // all waves done reading As before sgnL overwrites As[0]

    signed char* sgnL = &As[0][0];     // [64 px][16 chunks][16 B] = 16 KB

    // ---- epi1: out1 -> 64 static VGPRs; sign(out1+b21) -> swizzled LDS ----
    float out1r[4][4][4];
    #pragma unroll
    for (int j = 0; j < 4; ++j) {
        const int o = wid * 64 + j * 16 + l16;
        const float sc = k2s[o], bt = k2b[o];
        const float v12 = b12[o], v13 = b13[o], v21 = b21[o], va = a1[o];
        #pragma unroll
        for (int i = 0; i < 4; ++i) {
            const int p0 = p0t + i * 16 + quad * 4;
            const float4 xv = *(const float4*)(x + ((size_t)(n * CCH + o)) * PIMG + p0);
            float rr[4] = {xv.x, xv.y, xv.z, xv.w};
            #pragma unroll
            for (int r = 0; r < 4; ++r) {
                float v  = (float)acc[i][j][r] * sc + bt + rr[r];
                float tt = v + v12;
                float o1 = ((tt > 0.f) ? tt : va * tt) + v13;
                out1r[i][j][r] = o1;
                const int pl = i * 16 + quad * 4 + r;      // local pixel 0..63
                sgnL[pl * 256 + (((wid * 4 + j) ^ (pl & 15)) << 4) + l16] =
                    sgnc(o1 + v21);
            }
        }
    }
    __syncthreads();

    // ---- GEMM2: 1x1 conv, K=256 in 4 straight-line phases ----
    intx4 acc2[4][4] = {};
    #pragma unroll
    for (int ph = 0; ph < 4; ++ph) {
        const int cbg2 = ph >> 1, ks2 = ph & 1;
        intx4 af2[4], bf2[4];
        const signed char* bp = wq1f +
            (size_t)(((cbg2 * 2 + ks2) * 16 + wid * 4) * 1024) + lane * 16;
        #pragma unroll
        for (int j = 0; j < 4; ++j) bf2[j] = *(const intx4*)(bp + j * 1024);
        const int q16 = cbg2 * 8 + ks2 * 4 + quad;
        #pragma unroll
        for (int i = 0; i < 4; ++i) {
            const int m = i * 16 + l16;
            af2[i] = *(const intx4*)(&sgnL[m * 256 + ((q16 ^ (m & 15)) << 4)]);
        }
        #pragma unroll
        for (int i = 0; i < 4; ++i)
            #pragma unroll
            for (int j = 0; j < 4; ++j)
                acc2[i][j] = __builtin_amdgcn_mfma_i32_16x16x64_i8(
                    af2[i], bf2[j], acc2[i][j], 0, 0, 0);
    }

    // ---- epi2: final out from out1 regs ----
    #pragma unroll
    for (int j = 0; j < 4; ++j) {
        const int o = wid * 64 + j * 16 + l16;
        const float sc = k3s[o], bt = k3b[o];
        const float v22 = b22[o], v23 = b23[o], va = a2[o];
        #pragma unroll
        for (int i = 0; i < 4; ++i) {
            const int p0 = p0t + i * 16 + quad * 4;
            float res[4];
            #pragma unroll
            for (int r = 0; r < 4; ++r) {
                float v  = (float)acc2[i][j][r] * sc + bt + out1r[i][j][r];
                float tt = v + v22;
                res[r] = ((tt > 0.f) ? tt : va * tt) + v23;
            }
            float4 ov; ov.x = res[0]; ov.y = res[1]; ov.z = res[2]; ov.w = res[3];
            *(float4*)(out + ((size_t)(n * CCH + o)) * PIMG + p0) = ov;
        }
    }
}

// ---------------- launch ---------------------------------------------------
extern "C" void kernel_launch(void* const* d_in, const int* in_sizes, int n_in,
                              void* d_out, int out_size, void* d_ws, size_t ws_size,
                              hipStream_t stream) {
    const float* x   = (const float*)d_in[0];
    const float* w3  = (const float*)d_in[1];
    const float* w1  = (const float*)d_in[2];
    const float* b11 = (const float*)d_in[3];
    const float* b12 = (const float*)d_in[4];
    const float* b13 = (const float*)d_in[5];
    const float* b21 = (const float*)d_in[6];
    const float* b22 = (const float*)d_in[7];
    const float* b23 = (const float*)d_in[8];
    const float* g1  = (const float*)d_in[9];
    const float* be1 = (const float*)d_in[10];
    const float* m1  = (const float*)d_in[11];
    const float* v1  = (const float*)d_in[12];
    const float* g2  = (const float*)d_in[13];
    const float* be2 = (const float*)d_in[14];
    const float* m2  = (const float*)d_in[15];
    const float* v2  = (const float*)d_in[16];
    const float* a1  = (const float*)d_in[17];
    const float* a2  = (const float*)d_in[18];
    float* out = (float*)d_out;

    char* ws = (char*)d_ws;
    // spad:  2*32*3364*128 i8 = 27,553,792 B (+256 KB staging-overrun slack)
    // wq3f:  36*16384 i8      =    589,824 B
    // wq1f:  4*16384 i8       =     65,536 B
    signed char* spad = (signed char*)(ws);
    signed char* wq3f = (signed char*)(ws + 27816192);
    signed char* wq1f = (signed char*)(ws + 28406016);
    float* k2s = (float*)(ws + 28471552);
    float* k2b = k2s + 256;
    float* k3s = k2s + 512;
    float* k3b = k2s + 768;

    transpose_sign<<<dim3(58, 2, 32), 256, 0, stream>>>(x, b11, spad);
    prep_w<<<512, 256, 0, stream>>>(w3, w1, g1, be1, m1, v1, g2, be2, m2, v2,
                                    wq3f, wq1f, k2s, k2b, k3s, k3b);
    gemm_fused<<<dim3(49, 32), 256, 0, stream>>>(spad, wq3f, wq1f, x,
                                                 k2s, k2b, k3s, k3b,
                                                 b12, b13, b21, a1,
                                                 b22, b23, a2, out);
}